// Round 2
// baseline (22155.638 us; speedup 1.0000x reference)
//
#include <hip/hip_runtime.h>
#include <math.h>
#include <stdint.h>

// Problem constants (T=1024, B=64, D=512, H=512), fp32 everywhere.
#define TT      1024
#define BATCH   64
#define HH      512
#define NG      8      // batch groups (8 rows each)
#define WPG     32     // workgroups per group (H split 512/16)
#define BSL     8      // batch rows per group
#define HSL     16     // output rows per workgroup
#define NTH     512    // threads per block (8 waves)

// LDS layout (floats). Staging rows are padded to SP2=516 (== 4 mod 8) so the
// compute-read pattern (lanes vary bb,ks -> byte addr bb*2064 + ks*16) lands on
// 8 DISTINCT 16B bank-groups {bb*16 + ks*4 mod 32}: conflict-free, 8-way bcast.
#define SP2     516
#define BUFX0   0
#define BUFX1   (8 * SP2)
#define BUFH0_  (16 * SP2)
#define BUFH1_  (24 * SP2)
#define SCR     (32 * SP2)
#define SCRS    17                       // scratch stride (pad vs 16)
#define LDS_FL  (SCR + 129 * SCRS)       // 18705 floats
#define LDS_BYTES (LDS_FL * 4)           // 74820 B (>=1 block/CU guaranteed)

// ---- LLC-coherent helpers (R1 lesson: relaxed SYSTEM scope => sc0|sc1, no
// whole-L2 writeback storms; ordering done manually with s_waitcnt) ----
__device__ __forceinline__ float2 sys_ld2(const float* p) {
    unsigned long long v = __hip_atomic_load((const unsigned long long*)p, __ATOMIC_RELAXED,
                                             __HIP_MEMORY_SCOPE_SYSTEM);
    union { unsigned long long u; float2 f; } cv; cv.u = v; return cv.f;
}
__device__ __forceinline__ void sys_st(float* p, float v) {
    __hip_atomic_store(p, v, __ATOMIC_RELAXED, __HIP_MEMORY_SCOPE_SYSTEM);
}
__device__ __forceinline__ void wait_vm0() {
    asm volatile("s_waitcnt vmcnt(0)" ::: "memory");
}
__device__ __forceinline__ void dot4(float4 w, float4 x, float& a) {
    a = fmaf(w.x, x.x, a); a = fmaf(w.y, x.y, a);
    a = fmaf(w.z, x.z, a); a = fmaf(w.w, x.w, a);
}

__global__ void __launch_bounds__(NTH, 2)
elman_persistent(const float* __restrict__ Xt,
                 const float* __restrict__ Wih0, const float* __restrict__ bih0,
                 const float* __restrict__ Whh0, const float* __restrict__ bhh0,
                 const float* __restrict__ Wih1, const float* __restrict__ bih1,
                 const float* __restrict__ Whh1, const float* __restrict__ bhh1,
                 float* __restrict__ out,   // [T][B][H], also serves as h1 history
                 float* h0buf,              // [2][B][H] double-buffered h0 (ws, zeroed)
                 unsigned* cnt)             // NG counters, 256B stride (ws, zeroed)
{
    extern __shared__ float lds[];
    const int tid = threadIdx.x;
    const int g   = blockIdx.x & 7;     // batch group
    const int w   = blockIdx.x >> 3;    // H-slice index
    const int jg0 = w * HSL;
    const int bg0 = g * BSL;

    // compute decomposition: tid = jp(3b) | bb(1b) | ks(5b); thread tile j_t=2, b_t=4
    const int jp   = tid & 7;
    const int bb4  = ((tid >> 3) & 1) * 4;
    const int ks   = tid >> 4;          // 0..31 (k-reduction width 32)
    const int kb   = ks * 4;            // k elements = kb + u*128 + 0..3
    const int lane = tid & 63;
    const int wv   = tid >> 6;

    // staging mapping: each wave stores one contiguous b-row slice
    const int row = tid >> 6;           // 0..7
    const int kst = (tid & 63) * 4;     // 0..252

    // ---- time-invariant weights -> VGPRs: 2 rows x 16 k x 4 mats = 128 regs ----
    float4 wr[4][2][4];
    {
        const float* const Ws[4] = {Wih0, Whh0, Wih1, Whh1};
        #pragma unroll
        for (int m = 0; m < 4; ++m)
            #pragma unroll
            for (int jj = 0; jj < 2; ++jj) {
                const float* src = Ws[m] + (size_t)(jg0 + jp * 2 + jj) * HH + kb;
                #pragma unroll
                for (int u = 0; u < 4; ++u)
                    wr[m][jj][u] = *(const float4*)(src + u * 128);
            }
    }

    float bias = 0.f;
    if (tid < 256) {
        const int l = tid >> 7, jx = jg0 + (tid & 15);
        bias = l ? (bih1[jx] + bhh1[jx]) : (bih0[jx] + bhh0[jx]);
    }

    // prologue: stage x[0] into buffer 0
    {
        const float* xs = Xt + (size_t)(bg0 + row) * HH + kst;
        *(float4*)(lds + BUFX0 + row * SP2 + kst)       = *(const float4*)(xs);
        *(float4*)(lds + BUFX0 + row * SP2 + kst + 256) = *(const float4*)(xs + 256);
    }
    __syncthreads();

    const float* xload  = Xt  + ((size_t)BATCH + bg0 + row) * HH + kst;   // x[1]
    const float* h1load = out + (size_t)(bg0 + row) * HH + kst;           // out[0]

    unsigned* mycnt = cnt + g * 64;      // 256B stride between group counters
    unsigned target = 0;
    bool     dead   = false;            // barrier watchdog tripped

    for (int p = 0; p <= TT; ++p) {
        const bool doL0  = (p < TT);
        const bool doL1  = (p >= 1);
        const bool hasH1 = (p >= 2);
        const bool pre   = (p + 1 < TT);
        const int  cur   = p & 1;

        // 1. issue h loads (LLC) — latency covered by the x-pass below
        float2 h0a, h0b, h0c, h0d;
        {
            const float* hs = h0buf + (size_t)((p + 1) & 1) * (BATCH * HH)
                            + (size_t)(bg0 + row) * HH + kst;
            h0a = sys_ld2(hs);       h0b = sys_ld2(hs + 2);
            h0c = sys_ld2(hs + 256); h0d = sys_ld2(hs + 258);
        }
        float2 h1a = {0.f, 0.f}, h1b = h1a, h1c = h1a, h1d = h1a;
        if (hasH1) {
            h1a = sys_ld2(h1load);       h1b = sys_ld2(h1load + 2);
            h1c = sys_ld2(h1load + 256); h1d = sys_ld2(h1load + 258);
            h1load += BATCH * HH;
        }
        // 2. issue next-phase x loads (plain cached; consumed after the tail)
        float4 xn0, xn1;
        if (pre) { xn0 = *(const float4*)(xload); xn1 = *(const float4*)(xload + 256);
                   xload += BATCH * HH; }

        float acc0[2][4], acc1[2][4];
        #pragma unroll
        for (int jj = 0; jj < 2; ++jj)
            #pragma unroll
            for (int bi = 0; bi < 4; ++bi) { acc0[jj][bi] = 0.f; acc1[jj][bi] = 0.f; }

        // 3. x-pass: x[p] was staged during phase p-1 -> starts with ZERO wait
        if (doL0) {
            const float* bx = lds + (cur ? BUFX1 : BUFX0);
            #pragma unroll
            for (int u = 0; u < 4; ++u)
                #pragma unroll
                for (int bi = 0; bi < 4; ++bi) {
                    float4 xv = *(const float4*)(bx + (bb4 + bi) * SP2 + kb + u * 128);
                    dot4(wr[0][0][u], xv, acc0[0][bi]);
                    dot4(wr[0][1][u], xv, acc0[1][bi]);
                }
        }
        __builtin_amdgcn_sched_barrier(0);  // keep x-pass ahead of the h vmcnt stall

        // 4. stage h into LDS (contiguous 1KB per wave-instruction, conflict-free)
        *(float4*)(lds + BUFH0_ + row * SP2 + kst)       = make_float4(h0a.x, h0a.y, h0b.x, h0b.y);
        *(float4*)(lds + BUFH0_ + row * SP2 + kst + 256) = make_float4(h0c.x, h0c.y, h0d.x, h0d.y);
        if (hasH1) {
            *(float4*)(lds + BUFH1_ + row * SP2 + kst)       = make_float4(h1a.x, h1a.y, h1b.x, h1b.y);
            *(float4*)(lds + BUFH1_ + row * SP2 + kst + 256) = make_float4(h1c.x, h1c.y, h1d.x, h1d.y);
        }
        __syncthreads();

        // 5. h0-pass (Whh0 -> acc0, Wih1 -> acc1), then h1-pass (Whh1 -> acc1)
        auto h0pass = [&](bool d0, bool d1) {
            #pragma unroll
            for (int u = 0; u < 4; ++u)
                #pragma unroll
                for (int bi = 0; bi < 4; ++bi) {
                    float4 hv = *(const float4*)(lds + BUFH0_ + (bb4 + bi) * SP2 + kb + u * 128);
                    if (d0) { dot4(wr[1][0][u], hv, acc0[0][bi]);
                              dot4(wr[1][1][u], hv, acc0[1][bi]); }
                    if (d1) { dot4(wr[2][0][u], hv, acc1[0][bi]);
                              dot4(wr[2][1][u], hv, acc1[1][bi]); }
                }
        };
        if (doL0 && doL1) h0pass(true, true);
        else if (doL0)    h0pass(true, false);
        else              h0pass(false, true);
        if (hasH1) {
            #pragma unroll
            for (int u = 0; u < 4; ++u)
                #pragma unroll
                for (int bi = 0; bi < 4; ++bi) {
                    float4 hv = *(const float4*)(lds + BUFH1_ + (bb4 + bi) * SP2 + kb + u * 128);
                    dot4(wr[3][0][u], hv, acc1[0][bi]);
                    dot4(wr[3][1][u], hv, acc1[1][bi]);
                }
        }

        // 6. reduce over ks: 4-way in-wave, then 8 waves via LDS scratch
        #pragma unroll
        for (int jj = 0; jj < 2; ++jj)
            #pragma unroll
            for (int bi = 0; bi < 4; ++bi) {
                acc0[jj][bi] += __shfl_xor(acc0[jj][bi], 16);
                acc0[jj][bi] += __shfl_xor(acc0[jj][bi], 32);
                acc1[jj][bi] += __shfl_xor(acc1[jj][bi], 16);
                acc1[jj][bi] += __shfl_xor(acc1[jj][bi], 32);
            }
        if (lane < 16) {   // lane = jp + 8*bb (ks&3 == 0 holds the 4-way sums)
            #pragma unroll
            for (int jj = 0; jj < 2; ++jj)
                #pragma unroll
                for (int bi = 0; bi < 4; ++bi) {
                    lds[SCR + (wv * 16 + jj * 4 + bi) * SCRS + lane]     = acc0[jj][bi];
                    lds[SCR + (wv * 16 + 8 + jj * 4 + bi) * SCRS + lane] = acc1[jj][bi];
                }
        }
        __syncthreads();

        // 7. tail: 8-way sum, bias, tanh, LLC store
        if (tid < 256) {
            const int l    = tid >> 7;
            const int jloc = tid & 15;                 // j = jg0 + jloc (= jp*2+jj)
            const int blo  = (tid >> 4) & 7;           // b = bg0 + blo (= bb*4+bi)
            const int a    = l * 8 + (jloc & 1) * 4 + (blo & 3);
            const int ll   = (jloc >> 1) + 8 * (blo >> 2);
            float s = 0.f;
            #pragma unroll
            for (int wq = 0; wq < 8; ++wq)
                s += lds[SCR + (wq * 16 + a) * SCRS + ll];
            float val = tanhf(s + bias);
            if (l == 0) {
                if (doL0) sys_st(h0buf + (size_t)cur * (BATCH * HH)
                                 + (size_t)(bg0 + blo) * HH + jg0 + jloc, val);
            } else {
                if (doL1) sys_st(out + ((size_t)(p - 1) * BATCH + bg0 + blo) * HH + jg0 + jloc, val);
            }
        }
        wait_vm0();
        __syncthreads();

        // 8. stage x[p+1] into the other buffer (overlaps the group barrier)
        if (pre) {
            float* bx = lds + (cur ? BUFX0 : BUFX1);
            *(float4*)(bx + row * SP2 + kst)       = xn0;
            *(float4*)(bx + row * SP2 + kst + 256) = xn1;
        }

        // 9. group barrier: relaxed RMW arrival + relaxed poll at the LLC.
        //    Watchdog: if a peer never arrives (~0.1 s), trip `dead` and stop
        //    waiting for the remainder of the run -> fast wrong-answer instead
        //    of a container-killing GPU hang (diagnostic, costs nothing when ok).
        if (tid == 0) {
            __hip_atomic_fetch_add(mycnt, 1u, __ATOMIC_RELAXED, __HIP_MEMORY_SCOPE_SYSTEM);
            target += WPG;
            if (!dead) {
                unsigned spins = 0;
                while (__hip_atomic_load(mycnt, __ATOMIC_RELAXED, __HIP_MEMORY_SCOPE_SYSTEM) < target) {
                    __builtin_amdgcn_s_sleep(2);
                    if (++spins > (1u << 21)) { dead = true; break; }
                }
            }
            asm volatile("" ::: "memory");
        } else {
            target += WPG;
        }
        __syncthreads();
    }
}

extern "C" void kernel_launch(void* const* d_in, const int* in_sizes, int n_in,
                              void* d_out, int out_size, void* d_ws, size_t ws_size,
                              hipStream_t stream) {
    (void)in_sizes; (void)n_in; (void)out_size; (void)ws_size;
    const float* Xt   = (const float*)d_in[0];
    const float* Wih0 = (const float*)d_in[1];
    const float* bih0 = (const float*)d_in[2];
    const float* Whh0 = (const float*)d_in[3];
    const float* bhh0 = (const float*)d_in[4];
    const float* Wih1 = (const float*)d_in[5];
    const float* bih1 = (const float*)d_in[6];
    const float* Whh1 = (const float*)d_in[7];
    const float* bhh1 = (const float*)d_in[8];
    float*    out   = (float*)d_out;
    float*    h0buf = (float*)d_ws;                          // 2*64*512 floats
    unsigned* cnt   = (unsigned*)((char*)d_ws + 2 * BATCH * HH * 4);  // 8 counters, 256B stride

    hipFuncSetAttribute((const void*)elman_persistent,
                        hipFuncAttributeMaxDynamicSharedMemorySize, LDS_BYTES);
    hipMemsetAsync(d_ws, 0, 2 * BATCH * HH * 4 + NG * 256, stream);

    elman_persistent<<<dim3(NG * WPG), dim3(NTH), LDS_BYTES, stream>>>(
        Xt, Wih0, bih0, Whh0, bhh0, Wih1, bih1, Whh1, bhh1, out, h0buf, cnt);
}

// Round 3
// 7005.894 us; speedup vs baseline: 3.1624x; 3.1624x over previous
//
#include <hip/hip_runtime.h>
#include <math.h>
#include <stdint.h>

// Problem constants (T=1024, B=64, D=512, H=512), fp32 everywhere.
#define TT      1024
#define BATCH   64
#define HH      512
#define NG      8      // batch groups (8 rows each)
#define WPG     32     // workgroups per group (H split 512/16)
#define BSL     8      // batch rows per group
#define HSL     16     // output rows per workgroup
#define NTH     512    // threads per block (8 waves)

// LDS layout (floats). Rows padded to SPW=516 (SPW/4=129 odd) so that
//  - weight reads  (lanes vary jp,ks2): 32 unique 16B lines spread 4-per-bank-group (floor)
//  - activation reads (lanes vary bb,bi,ks2; 8-way jp broadcast): 8 lines on 8 groups (floor)
//  - staging writes: 64 consecutive float4 per wave (conflict-free)
#define SPW     516
#define WLDS    (3 * 16 * SPW)          // Whh0, Wih1, Whh1 : 24768 floats
#define BUFH0   WLDS                    // h0 staging [8][SPW]
#define BUFH1   (WLDS + 8 * SPW)        // h1 staging [8][SPW]
#define SCR     (WLDS + 16 * SPW)       // reduce scratch 129*17
#define SCRS    17
#define LDS_FL  (SCR + 129 * SCRS)      // 35217 floats
#define LDS_BYTES (LDS_FL * 4)          // 140868 B -> 1 block/CU

// ---- LLC-coherent helpers (relaxed SYSTEM scope => sc0|sc1 loads/stores,
// complete at Infinity Cache, no L2 writeback storms; order via s_waitcnt) ----
__device__ __forceinline__ float2 sys_ld2(const float* p) {
    unsigned long long v = __hip_atomic_load((const unsigned long long*)p, __ATOMIC_RELAXED,
                                             __HIP_MEMORY_SCOPE_SYSTEM);
    union { unsigned long long u; float2 f; } cv; cv.u = v; return cv.f;
}
__device__ __forceinline__ void sys_st(float* p, float v) {
    __hip_atomic_store(p, v, __ATOMIC_RELAXED, __HIP_MEMORY_SCOPE_SYSTEM);
}
__device__ __forceinline__ void wait_vm0() {
    asm volatile("s_waitcnt vmcnt(0)" ::: "memory");
}
__device__ __forceinline__ void dot4(float4 w, float4 x, float& a) {
    a = fmaf(w.x, x.x, a); a = fmaf(w.y, x.y, a);
    a = fmaf(w.z, x.z, a); a = fmaf(w.w, x.w, a);
}

// ============================================================================
// Kernel 1: Z0 = Xt @ Wih0^T + bih0, written into `out` (aliasing is safe:
// out[t] is consumed as Z0 at phase t and only overwritten at phase t+1;
// all later readers of out use LLC-scope loads).
// M = T*B = 65536, N = 512, K = 512.  64x64 tile, 256 thr, 4x4 microtile.
// ============================================================================
__global__ void __launch_bounds__(256)
z0_gemm(const float* __restrict__ X, const float* __restrict__ W,
        const float* __restrict__ bih, float* __restrict__ Z)
{
    __shared__ float As[32][68];   // [k][m], pad 68 (68 mod 8 = 4) spreads banks
    __shared__ float Bs[32][68];   // [k][n]
    const int tid = threadIdx.x;
    const int tx  = tid & 15, ty = tid >> 4;
    const int n0  = (blockIdx.x & 7) * 64;
    const int m0  = (blockIdx.x >> 3) * 64;
    const int lm  = tid >> 3;            // 0..31
    const int lk  = (tid & 7) * 4;       // 0..28

    float4 bb;
    bb.x = bih[n0 + tx * 4 + 0]; bb.y = bih[n0 + tx * 4 + 1];
    bb.z = bih[n0 + tx * 4 + 2]; bb.w = bih[n0 + tx * 4 + 3];

    float acc[4][4];
    #pragma unroll
    for (int i = 0; i < 4; ++i)
        #pragma unroll
        for (int j = 0; j < 4; ++j) acc[i][j] = 0.f;

    for (int k0 = 0; k0 < 512; k0 += 32) {
        float4 a0 = *(const float4*)(X + (size_t)(m0 + lm) * 512 + k0 + lk);
        float4 a1 = *(const float4*)(X + (size_t)(m0 + lm + 32) * 512 + k0 + lk);
        float4 b0 = *(const float4*)(W + (size_t)(n0 + lm) * 512 + k0 + lk);
        float4 b1 = *(const float4*)(W + (size_t)(n0 + lm + 32) * 512 + k0 + lk);
        __syncthreads();               // previous chunk fully consumed
        As[lk + 0][lm] = a0.x; As[lk + 1][lm] = a0.y;
        As[lk + 2][lm] = a0.z; As[lk + 3][lm] = a0.w;
        As[lk + 0][lm + 32] = a1.x; As[lk + 1][lm + 32] = a1.y;
        As[lk + 2][lm + 32] = a1.z; As[lk + 3][lm + 32] = a1.w;
        Bs[lk + 0][lm] = b0.x; Bs[lk + 1][lm] = b0.y;
        Bs[lk + 2][lm] = b0.z; Bs[lk + 3][lm] = b0.w;
        Bs[lk + 0][lm + 32] = b1.x; Bs[lk + 1][lm + 32] = b1.y;
        Bs[lk + 2][lm + 32] = b1.z; Bs[lk + 3][lm + 32] = b1.w;
        __syncthreads();
        #pragma unroll
        for (int kk = 0; kk < 32; ++kk) {
            float4 av = *(const float4*)(&As[kk][ty * 4]);
            float4 bv = *(const float4*)(&Bs[kk][tx * 4]);
            dot_unused:;
            acc[0][0] = fmaf(av.x, bv.x, acc[0][0]); acc[0][1] = fmaf(av.x, bv.y, acc[0][1]);
            acc[0][2] = fmaf(av.x, bv.z, acc[0][2]); acc[0][3] = fmaf(av.x, bv.w, acc[0][3]);
            acc[1][0] = fmaf(av.y, bv.x, acc[1][0]); acc[1][1] = fmaf(av.y, bv.y, acc[1][1]);
            acc[1][2] = fmaf(av.y, bv.z, acc[1][2]); acc[1][3] = fmaf(av.y, bv.w, acc[1][3]);
            acc[2][0] = fmaf(av.z, bv.x, acc[2][0]); acc[2][1] = fmaf(av.z, bv.y, acc[2][1]);
            acc[2][2] = fmaf(av.z, bv.z, acc[2][2]); acc[2][3] = fmaf(av.z, bv.w, acc[2][3]);
            acc[3][0] = fmaf(av.w, bv.x, acc[3][0]); acc[3][1] = fmaf(av.w, bv.y, acc[3][1]);
            acc[3][2] = fmaf(av.w, bv.z, acc[3][2]); acc[3][3] = fmaf(av.w, bv.w, acc[3][3]);
        }
    }
    #pragma unroll
    for (int i = 0; i < 4; ++i) {
        float4 r;
        r.x = acc[i][0] + bb.x; r.y = acc[i][1] + bb.y;
        r.z = acc[i][2] + bb.z; r.w = acc[i][3] + bb.w;
        *(float4*)(Z + (size_t)(m0 + ty * 4 + i) * 512 + n0 + tx * 4) = r;
    }
}

// ============================================================================
// Kernel 2: persistent 3-matmul recurrence.  Weights in LDS (proven resident),
// h0/h1 staged whole (no ring), Z0 term read from `out` per phase.
// ============================================================================
__global__ void __launch_bounds__(NTH, 2)
elman_persistent(const float* __restrict__ Whh0, const float* __restrict__ bhh0,
                 const float* __restrict__ Wih1, const float* __restrict__ bih1,
                 const float* __restrict__ Whh1, const float* __restrict__ bhh1,
                 float* __restrict__ out,   // [T][B][H]: Z0 on entry, h1 history on exit
                 float* h0buf,              // [2][B][H] double-buffered h0 (ws, zeroed)
                 unsigned* cnt)             // NG counters, 256B stride (ws, zeroed)
{
    extern __shared__ float lds[];
    const int tid = threadIdx.x;
    const int g   = blockIdx.x & 7;     // batch group
    const int w   = blockIdx.x >> 3;    // H-slice index
    const int jg0 = w * HSL;
    const int bg0 = g * BSL;

    // compute decomposition: tid = ks(5b)<<4 | bb(1b)<<3 | jp(3b); j_t=2, b_t=4
    const int jp   = tid & 7;
    const int bb4  = ((tid >> 3) & 1) * 4;
    const int ks   = tid >> 4;          // 0..31
    const int kb   = ks * 4;
    const int lane = tid & 63;
    const int wv   = tid >> 6;

    // staging mapping: each wave stores one contiguous b-row slice
    const int row = tid >> 6;           // 0..7
    const int kst = (tid & 63) * 4;     // 0..252

    // ---- one-time: stage 3 weight mats (rows jg0..jg0+15) into LDS ----
    {
        const float* const Ws[3] = {Whh0, Wih1, Whh1};
        for (int f = tid; f < 48 * 128; f += NTH) {
            const int jj = f >> 7, k4 = f & 127;
            const float* src = Ws[jj >> 4] + (size_t)(jg0 + (jj & 15)) * HH;
            *(float4*)(lds + jj * SPW + k4 * 4) = ((const float4*)src)[k4];
        }
    }
    float bias = 0.f;
    if (tid < 256) {
        const int l = tid >> 7, jx = jg0 + (tid & 15);
        bias = l ? (bih1[jx] + bhh1[jx]) : bhh0[jx];
    }
    __syncthreads();

    const float* h1load = out + (size_t)(bg0 + row) * HH + kst;   // out[0] slice

    unsigned* mycnt = cnt + g * 64;      // 256B stride between group counters
    unsigned target = 0;
    bool     dead   = false;             // barrier watchdog

    for (int p = 0; p <= TT; ++p) {
        const bool doL0  = (p < TT);
        const bool doL1  = (p >= 1);
        const bool hasH1 = (p >= 2);
        const int  cur   = p & 1;

        // 1. issue all global loads for this phase
        float2 h0a, h0b, h0c, h0d;
        {
            const float* hs = h0buf + (size_t)((p + 1) & 1) * (BATCH * HH)
                            + (size_t)(bg0 + row) * HH + kst;
            h0a = sys_ld2(hs);       h0b = sys_ld2(hs + 2);
            h0c = sys_ld2(hs + 256); h0d = sys_ld2(hs + 258);
        }
        float2 h1a = {0.f, 0.f}, h1b = h1a, h1c = h1a, h1d = h1a;
        if (hasH1) {
            h1a = sys_ld2(h1load);       h1b = sys_ld2(h1load + 2);
            h1c = sys_ld2(h1load + 256); h1d = sys_ld2(h1load + 258);
            h1load += BATCH * HH;
        }
        float z0v = 0.f;    // layer-0 precomputed input term (plain cached load:
        if (doL0 && tid < 128)  // slot out[p] not yet rewritten, never re-read plainly)
            z0v = out[((size_t)p * BATCH + bg0 + (tid >> 4)) * HH + jg0 + (tid & 15)];

        // 2. stage h0/h1 into LDS
        wait_vm0();
        *(float4*)(lds + BUFH0 + row * SPW + kst)       = make_float4(h0a.x, h0a.y, h0b.x, h0b.y);
        *(float4*)(lds + BUFH0 + row * SPW + kst + 256) = make_float4(h0c.x, h0c.y, h0d.x, h0d.y);
        if (hasH1) {
            *(float4*)(lds + BUFH1 + row * SPW + kst)       = make_float4(h1a.x, h1a.y, h1b.x, h1b.y);
            *(float4*)(lds + BUFH1 + row * SPW + kst + 256) = make_float4(h1c.x, h1c.y, h1d.x, h1d.y);
        }
        __syncthreads();                                   // S1

        float acc0[2][4], acc1[2][4];
        #pragma unroll
        for (int jj = 0; jj < 2; ++jj)
            #pragma unroll
            for (int bi = 0; bi < 4; ++bi) { acc0[jj][bi] = 0.f; acc1[jj][bi] = 0.f; }

        // 3. h0-pass: Whh0 (mat 0) -> acc0, Wih1 (mat 1) -> acc1
        #pragma unroll
        for (int u = 0; u < 4; ++u) {
            const int wo = kb + u * 128;
            float4 wa0 = *(const float4*)(lds + (0 * 16 + jp * 2 + 0) * SPW + wo);
            float4 wa1 = *(const float4*)(lds + (0 * 16 + jp * 2 + 1) * SPW + wo);
            float4 wb0 = *(const float4*)(lds + (1 * 16 + jp * 2 + 0) * SPW + wo);
            float4 wb1 = *(const float4*)(lds + (1 * 16 + jp * 2 + 1) * SPW + wo);
            #pragma unroll
            for (int bi = 0; bi < 4; ++bi) {
                float4 hv = *(const float4*)(lds + BUFH0 + (bb4 + bi) * SPW + wo);
                dot4(wa0, hv, acc0[0][bi]);
                dot4(wa1, hv, acc0[1][bi]);
                dot4(wb0, hv, acc1[0][bi]);
                dot4(wb1, hv, acc1[1][bi]);
            }
        }
        // 4. h1-pass: Whh1 (mat 2) -> acc1
        if (hasH1) {
            #pragma unroll
            for (int u = 0; u < 4; ++u) {
                const int wo = kb + u * 128;
                float4 wc0 = *(const float4*)(lds + (2 * 16 + jp * 2 + 0) * SPW + wo);
                float4 wc1 = *(const float4*)(lds + (2 * 16 + jp * 2 + 1) * SPW + wo);
                #pragma unroll
                for (int bi = 0; bi < 4; ++bi) {
                    float4 hv = *(const float4*)(lds + BUFH1 + (bb4 + bi) * SPW + wo);
                    dot4(wc0, hv, acc1[0][bi]);
                    dot4(wc1, hv, acc1[1][bi]);
                }
            }
        }

        // 5. reduce over ks: 4-way in-wave, then 8 waves via LDS scratch
        #pragma unroll
        for (int jj = 0; jj < 2; ++jj)
            #pragma unroll
            for (int bi = 0; bi < 4; ++bi) {
                acc0[jj][bi] += __shfl_xor(acc0[jj][bi], 16);
                acc0[jj][bi] += __shfl_xor(acc0[jj][bi], 32);
                acc1[jj][bi] += __shfl_xor(acc1[jj][bi], 16);
                acc1[jj][bi] += __shfl_xor(acc1[jj][bi], 32);
            }
        if (lane < 16) {   // lane = jp + 8*bb holds the 4-way sums
            #pragma unroll
            for (int jj = 0; jj < 2; ++jj)
                #pragma unroll
                for (int bi = 0; bi < 4; ++bi) {
                    lds[SCR + (wv * 16 + jj * 4 + bi) * SCRS + lane]     = acc0[jj][bi];
                    lds[SCR + (wv * 16 + 8 + jj * 4 + bi) * SCRS + lane] = acc1[jj][bi];
                }
        }
        __syncthreads();                                   // S2

        // 6. tail: 8-way sum, + z0 + bias, tanh, LLC store
        if (tid < 256) {
            const int l    = tid >> 7;
            const int jloc = tid & 15;                 // j = jg0 + jloc (= jp*2+jj)
            const int blo  = (tid >> 4) & 7;           // b = bg0 + blo (= bb*4+bi)
            const int a    = l * 8 + (jloc & 1) * 4 + (blo & 3);
            const int ll   = (jloc >> 1) + 8 * (blo >> 2);
            float s = 0.f;
            #pragma unroll
            for (int wq = 0; wq < 8; ++wq)
                s += lds[SCR + (wq * 16 + a) * SCRS + ll];
            float val = tanhf(s + bias + z0v);        // z0v == 0 for layer 1
            if (l == 0) {
                if (doL0) sys_st(h0buf + (size_t)cur * (BATCH * HH)
                                 + (size_t)(bg0 + blo) * HH + jg0 + jloc, val);
            } else {
                if (doL1) sys_st(out + ((size_t)(p - 1) * BATCH + bg0 + blo) * HH + jg0 + jloc, val);
            }
        }
        wait_vm0();
        __syncthreads();                                   // S3: all stores drained

        // 7. group barrier: relaxed RMW arrival + relaxed poll at the LLC
        if (tid == 0) {
            __hip_atomic_fetch_add(mycnt, 1u, __ATOMIC_RELAXED, __HIP_MEMORY_SCOPE_SYSTEM);
            target += WPG;
            if (!dead) {
                unsigned spins = 0;
                while (__hip_atomic_load(mycnt, __ATOMIC_RELAXED, __HIP_MEMORY_SCOPE_SYSTEM) < target) {
                    __builtin_amdgcn_s_sleep(2);
                    if (++spins > (1u << 21)) { dead = true; break; }
                }
            }
            asm volatile("" ::: "memory");
        } else {
            target += WPG;
        }
        __syncthreads();                                   // S4
    }
}

extern "C" void kernel_launch(void* const* d_in, const int* in_sizes, int n_in,
                              void* d_out, int out_size, void* d_ws, size_t ws_size,
                              hipStream_t stream) {
    (void)in_sizes; (void)n_in; (void)out_size; (void)ws_size;
    const float* Xt   = (const float*)d_in[0];
    const float* Wih0 = (const float*)d_in[1];
    const float* bih0 = (const float*)d_in[2];
    const float* Whh0 = (const float*)d_in[3];
    const float* bhh0 = (const float*)d_in[4];
    const float* Wih1 = (const float*)d_in[5];
    const float* bih1 = (const float*)d_in[6];
    const float* Whh1 = (const float*)d_in[7];
    const float* bhh1 = (const float*)d_in[8];
    float*    out   = (float*)d_out;
    float*    h0buf = (float*)d_ws;                          // 2*64*512 floats
    unsigned* cnt   = (unsigned*)((char*)d_ws + 2 * BATCH * HH * 4);  // 8 counters, 256B stride

    hipFuncSetAttribute((const void*)elman_persistent,
                        hipFuncAttributeMaxDynamicSharedMemorySize, LDS_BYTES);
    hipMemsetAsync(d_ws, 0, 2 * BATCH * HH * 4 + NG * 256, stream);

    // 1) Z0 = Xt@Wih0^T + bih0 -> out (stream-ordered; L2 flushed at kernel end)
    z0_gemm<<<dim3((TT * BATCH / 64) * (HH / 64)), dim3(256), 0, stream>>>(
        Xt, Wih0, bih0, out);

    // 2) persistent recurrence (3 matmuls/phase)
    elman_persistent<<<dim3(NG * WPG), dim3(NTH), LDS_BYTES, stream>>>(
        Whh0, bhh0, Wih1, bih1, Whh1, bhh1, out, h0buf, cnt);
}

// Round 6
// 6995.005 us; speedup vs baseline: 3.1674x; 1.0016x over previous
//
#include <hip/hip_runtime.h>
#include <math.h>
#include <stdint.h>

// Problem constants (T=1024, B=64, D=512, H=512), fp32 everywhere.
#define TT      1024
#define BATCH   64
#define HH      512
#define NG      8      // batch groups (8 rows each)
#define WPG     32     // workgroups per group (H split 512/16)
#define BSL     8      // batch rows per group
#define HSL     16     // output rows per workgroup
#define NTH     512    // threads per block (8 waves)

// ---- LDS layout (floats) ----
// Weights packed in wave-read order: [mat(3)][jj(2)][u(4)] blocks of 1024
// floats, inner = [ks(32)][jp(8)]·float4.  A wave's weight read (lanes vary
// ks_lo,jp; bb broadcast 2-way) is a lane-consecutive 1KB burst ->
// conflict-free (identical bank math to the staging writes, always clean).
#define WBLK(m, jj, u)  ((((m) * 2 + (jj)) * 4 + (u)) << 10)
#define WLDS    (24 * 1024)             // 24576 floats
// Activation buffers: row-major [8][SPW], SPW=516 -> read starts spread
// over 8 distinct bank-quads (8-way jp broadcast), staging writes canonical.
#define SPW     516
#define BUFH0   WLDS                    // h0 staging [8][SPW]
#define BUFH1   (WLDS + 8 * SPW)        // h1 staging [8][SPW]
#define SCR     (WLDS + 16 * SPW)       // reduce scratch 129*17 (R3-proven)
#define SCRS    17
#define LDS_FL  (SCR + 129 * SCRS)      // 35025 floats
#define LDS_BYTES (LDS_FL * 4)          // 140100 B -> 1 block/CU

// ---- LLC-coherent helpers (relaxed SYSTEM scope => sc0|sc1 loads/stores,
// complete at Infinity Cache, no L2 writeback storms; order via s_waitcnt) ----
__device__ __forceinline__ float2 sys_ld2(const float* p) {
    unsigned long long v = __hip_atomic_load((const unsigned long long*)p, __ATOMIC_RELAXED,
                                             __HIP_MEMORY_SCOPE_SYSTEM);
    union { unsigned long long u; float2 f; } cv; cv.u = v; return cv.f;
}
__device__ __forceinline__ void sys_st(float* p, float v) {
    __hip_atomic_store(p, v, __ATOMIC_RELAXED, __HIP_MEMORY_SCOPE_SYSTEM);
}
__device__ __forceinline__ void wait_vm0() {
    asm volatile("s_waitcnt vmcnt(0)" ::: "memory");
}
__device__ __forceinline__ void dot4(float4 w, float4 x, float& a) {
    a = fmaf(w.x, x.x, a); a = fmaf(w.y, x.y, a);
    a = fmaf(w.z, x.z, a); a = fmaf(w.w, x.w, a);
}

// ============================================================================
// Kernel 1: Z0 = Xt @ Wih0^T + bih0, written into `out` (aliasing safe:
// out[t] is consumed as Z0 at phase t and only overwritten at phase t+1;
// all post-overwrite readers use LLC-scope loads).
// ============================================================================
__global__ void __launch_bounds__(256)
z0_gemm(const float* __restrict__ X, const float* __restrict__ W,
        const float* __restrict__ bih, float* __restrict__ Z)
{
    __shared__ float As[32][68];
    __shared__ float Bs[32][68];
    const int tid = threadIdx.x;
    const int tx  = tid & 15, ty = tid >> 4;
    const int n0  = (blockIdx.x & 7) * 64;
    const int m0  = (blockIdx.x >> 3) * 64;
    const int lm  = tid >> 3;
    const int lk  = (tid & 7) * 4;

    float4 bb;
    bb.x = bih[n0 + tx * 4 + 0]; bb.y = bih[n0 + tx * 4 + 1];
    bb.z = bih[n0 + tx * 4 + 2]; bb.w = bih[n0 + tx * 4 + 3];

    float acc[4][4];
    #pragma unroll
    for (int i = 0; i < 4; ++i)
        #pragma unroll
        for (int j = 0; j < 4; ++j) acc[i][j] = 0.f;

    for (int k0 = 0; k0 < 512; k0 += 32) {
        float4 a0 = *(const float4*)(X + (size_t)(m0 + lm) * 512 + k0 + lk);
        float4 a1 = *(const float4*)(X + (size_t)(m0 + lm + 32) * 512 + k0 + lk);
        float4 b0 = *(const float4*)(W + (size_t)(n0 + lm) * 512 + k0 + lk);
        float4 b1 = *(const float4*)(W + (size_t)(n0 + lm + 32) * 512 + k0 + lk);
        __syncthreads();
        As[lk + 0][lm] = a0.x; As[lk + 1][lm] = a0.y;
        As[lk + 2][lm] = a0.z; As[lk + 3][lm] = a0.w;
        As[lk + 0][lm + 32] = a1.x; As[lk + 1][lm + 32] = a1.y;
        As[lk + 2][lm + 32] = a1.z; As[lk + 3][lm + 32] = a1.w;
        Bs[lk + 0][lm] = b0.x; Bs[lk + 1][lm] = b0.y;
        Bs[lk + 2][lm] = b0.z; Bs[lk + 3][lm] = b0.w;
        Bs[lk + 0][lm + 32] = b1.x; Bs[lk + 1][lm + 32] = b1.y;
        Bs[lk + 2][lm + 32] = b1.z; Bs[lk + 3][lm + 32] = b1.w;
        __syncthreads();
        #pragma unroll
        for (int kk = 0; kk < 32; ++kk) {
            float4 av = *(const float4*)(&As[kk][ty * 4]);
            float4 bv = *(const float4*)(&Bs[kk][tx * 4]);
            acc[0][0] = fmaf(av.x, bv.x, acc[0][0]); acc[0][1] = fmaf(av.x, bv.y, acc[0][1]);
            acc[0][2] = fmaf(av.x, bv.z, acc[0][2]); acc[0][3] = fmaf(av.x, bv.w, acc[0][3]);
            acc[1][0] = fmaf(av.y, bv.x, acc[1][0]); acc[1][1] = fmaf(av.y, bv.y, acc[1][1]);
            acc[1][2] = fmaf(av.y, bv.z, acc[1][2]); acc[1][3] = fmaf(av.y, bv.w, acc[1][3]);
            acc[2][0] = fmaf(av.z, bv.x, acc[2][0]); acc[2][1] = fmaf(av.z, bv.y, acc[2][1]);
            acc[2][2] = fmaf(av.z, bv.z, acc[2][2]); acc[2][3] = fmaf(av.z, bv.w, acc[2][3]);
            acc[3][0] = fmaf(av.w, bv.x, acc[3][0]); acc[3][1] = fmaf(av.w, bv.y, acc[3][1]);
            acc[3][2] = fmaf(av.w, bv.z, acc[3][2]); acc[3][3] = fmaf(av.w, bv.w, acc[3][3]);
        }
    }
    #pragma unroll
    for (int i = 0; i < 4; ++i) {
        float4 r;
        r.x = acc[i][0] + bb.x; r.y = acc[i][1] + bb.y;
        r.z = acc[i][2] + bb.z; r.w = acc[i][3] + bb.w;
        *(float4*)(Z + (size_t)(m0 + ty * 4 + i) * 512 + n0 + tx * 4) = r;
    }
}

// ============================================================================
// Kernel 2: persistent 3-matmul recurrence.  EXACT R3 skeleton (hardware-
// proven: single staging block + wait_vm0, in-phase z0 load, lambda-guarded
// passes, scalar scratch, counter barrier + watchdog).  ONE change vs R3:
// weights stored/read in the packed conflict-free LDS layout.
// ============================================================================
__global__ void __launch_bounds__(NTH, 2)
elman_persistent(const float* __restrict__ Whh0, const float* __restrict__ bhh0,
                 const float* __restrict__ Wih1, const float* __restrict__ bih1,
                 const float* __restrict__ Whh1, const float* __restrict__ bhh1,
                 float* __restrict__ out,   // [T][B][H]: Z0 on entry, h1 history on exit
                 float* h0buf,              // [2][B][H] double-buffered h0 (ws, zeroed)
                 unsigned* cnt)             // NG counters, 256B stride (ws, zeroed)
{
    extern __shared__ float lds[];
    const int tid = threadIdx.x;
    const int g   = blockIdx.x & 7;     // batch group
    const int w   = blockIdx.x >> 3;    // H-slice index
    const int jg0 = w * HSL;
    const int bg0 = g * BSL;

    // decomposition: tid = ks(5b)<<4 | bb(1b)<<3 | jp(3b); j_t=2, b_t=4
    const int jp   = tid & 7;
    const int bb4  = ((tid >> 3) & 1) * 4;
    const int ks   = tid >> 4;          // 0..31
    const int kb   = ks * 4;
    const int wofs = ks * 32 + jp * 4;  // packed-weight lane offset (floats)
    const int lane = tid & 63;
    const int wv   = tid >> 6;

    // staging mapping: wave wv stores b-row wv, lane-consecutive float4s
    const int row = tid >> 6;
    const int kst = (tid & 63) * 4;

    // ---- one-time: stage 3 weight mats into PACKED LDS layout ----
    {
        const float* const Ws[3] = {Whh0, Wih1, Whh1};
        for (int f = tid; f < 48 * 128; f += NTH) {
            const int jrow = f >> 7, k4 = f & 127;
            const int mat = jrow >> 4, r = jrow & 15;
            const int jp_ = r >> 1, jj_ = r & 1;
            const int u_ = k4 >> 5, ks_ = k4 & 31;
            float4 v = ((const float4*)(Ws[mat] + (size_t)(jg0 + r) * HH))[k4];
            *(float4*)(lds + WBLK(mat, jj_, u_) + ks_ * 32 + jp_ * 4) = v;
        }
    }
    float bias = 0.f;
    if (tid < 256) {
        const int l = tid >> 7, jx = jg0 + (tid & 15);
        bias = l ? (bih1[jx] + bhh1[jx]) : bhh0[jx];
    }
    __syncthreads();

    const float* h1load = out + (size_t)(bg0 + row) * HH + kst;   // out[0] slice

    unsigned* mycnt = cnt + g * 64;      // 256B stride between group counters
    unsigned target = 0;
    bool     dead   = false;             // barrier watchdog

    for (int p = 0; p <= TT; ++p) {
        const bool doL0  = (p < TT);
        const bool doL1  = (p >= 1);
        const bool hasH1 = (p >= 2);
        const int  cur   = p & 1;

        // 1. issue all global loads for this phase
        float2 h0a, h0b, h0c, h0d;
        {
            const float* hs = h0buf + (size_t)((p + 1) & 1) * (BATCH * HH)
                            + (size_t)(bg0 + row) * HH + kst;
            h0a = sys_ld2(hs);       h0b = sys_ld2(hs + 2);
            h0c = sys_ld2(hs + 256); h0d = sys_ld2(hs + 258);
        }
        float2 h1a = {0.f, 0.f}, h1b = h1a, h1c = h1a, h1d = h1a;
        if (hasH1) {
            h1a = sys_ld2(h1load);       h1b = sys_ld2(h1load + 2);
            h1c = sys_ld2(h1load + 256); h1d = sys_ld2(h1load + 258);
            h1load += BATCH * HH;
        }
        float z0v = 0.f;    // layer-0 precomputed input term (plain cached load:
        if (doL0 && tid < 128)  // slot out[p] not yet rewritten, never re-read plainly)
            z0v = out[((size_t)p * BATCH + bg0 + (tid >> 4)) * HH + jg0 + (tid & 15)];

        // 2. stage h0/h1 into LDS
        wait_vm0();
        *(float4*)(lds + BUFH0 + row * SPW + kst)       = make_float4(h0a.x, h0a.y, h0b.x, h0b.y);
        *(float4*)(lds + BUFH0 + row * SPW + kst + 256) = make_float4(h0c.x, h0c.y, h0d.x, h0d.y);
        if (hasH1) {
            *(float4*)(lds + BUFH1 + row * SPW + kst)       = make_float4(h1a.x, h1a.y, h1b.x, h1b.y);
            *(float4*)(lds + BUFH1 + row * SPW + kst + 256) = make_float4(h1c.x, h1c.y, h1d.x, h1d.y);
        }
        __syncthreads();                                   // S1

        float acc0[2][4], acc1[2][4];
        #pragma unroll
        for (int jj = 0; jj < 2; ++jj)
            #pragma unroll
            for (int bi = 0; bi < 4; ++bi) { acc0[jj][bi] = 0.f; acc1[jj][bi] = 0.f; }

        // 3. h0-pass: Whh0 (mat 0) -> acc0, Wih1 (mat 1) -> acc1
        auto h0pass = [&](bool d0, bool d1) {
            #pragma unroll
            for (int u = 0; u < 4; ++u) {
                float4 wa0 = *(const float4*)(lds + WBLK(0, 0, u) + wofs);
                float4 wa1 = *(const float4*)(lds + WBLK(0, 1, u) + wofs);
                float4 wb0 = *(const float4*)(lds + WBLK(1, 0, u) + wofs);
                float4 wb1 = *(const float4*)(lds + WBLK(1, 1, u) + wofs);
                #pragma unroll
                for (int bi = 0; bi < 4; ++bi) {
                    float4 hv = *(const float4*)(lds + BUFH0 + (bb4 + bi) * SPW + kb + u * 128);
                    if (d0) { dot4(wa0, hv, acc0[0][bi]);
                              dot4(wa1, hv, acc0[1][bi]); }
                    if (d1) { dot4(wb0, hv, acc1[0][bi]);
                              dot4(wb1, hv, acc1[1][bi]); }
                }
            }
        };
        if (doL0 && doL1) h0pass(true, true);
        else if (doL0)    h0pass(true, false);
        else              h0pass(false, true);
        // 4. h1-pass: Whh1 (mat 2) -> acc1
        if (hasH1) {
            #pragma unroll
            for (int u = 0; u < 4; ++u) {
                float4 wc0 = *(const float4*)(lds + WBLK(2, 0, u) + wofs);
                float4 wc1 = *(const float4*)(lds + WBLK(2, 1, u) + wofs);
                #pragma unroll
                for (int bi = 0; bi < 4; ++bi) {
                    float4 hv = *(const float4*)(lds + BUFH1 + (bb4 + bi) * SPW + kb + u * 128);
                    dot4(wc0, hv, acc1[0][bi]);
                    dot4(wc1, hv, acc1[1][bi]);
                }
            }
        }

        // 5. reduce over ks: 4-way in-wave, then 8 waves via LDS scratch
        #pragma unroll
        for (int jj = 0; jj < 2; ++jj)
            #pragma unroll
            for (int bi = 0; bi < 4; ++bi) {
                acc0[jj][bi] += __shfl_xor(acc0[jj][bi], 16);
                acc0[jj][bi] += __shfl_xor(acc0[jj][bi], 32);
                acc1[jj][bi] += __shfl_xor(acc1[jj][bi], 16);
                acc1[jj][bi] += __shfl_xor(acc1[jj][bi], 32);
            }
        if (lane < 16) {   // lane = bb*8+jp holds the 4-way sums
            #pragma unroll
            for (int jj = 0; jj < 2; ++jj)
                #pragma unroll
                for (int bi = 0; bi < 4; ++bi) {
                    lds[SCR + (wv * 16 + jj * 4 + bi) * SCRS + lane]     = acc0[jj][bi];
                    lds[SCR + (wv * 16 + 8 + jj * 4 + bi) * SCRS + lane] = acc1[jj][bi];
                }
        }
        __syncthreads();                                   // S2

        // 6. tail: 8-way sum, + z0 + bias, tanh, LLC store
        if (tid < 256) {
            const int l    = tid >> 7;
            const int jloc = tid & 15;                 // j = jg0 + jloc (= jp*2+jj)
            const int blo  = (tid >> 4) & 7;           // b = bg0 + blo (= bb*4+bi)
            const int a    = l * 8 + (jloc & 1) * 4 + (blo & 3);
            const int ll   = (jloc >> 1) + 8 * (blo >> 2);
            float s = 0.f;
            #pragma unroll
            for (int wq = 0; wq < 8; ++wq)
                s += lds[SCR + (wq * 16 + a) * SCRS + ll];
            float val = tanhf(s + bias + z0v);        // z0v == 0 for layer 1
            if (l == 0) {
                if (doL0) sys_st(h0buf + (size_t)cur * (BATCH * HH)
                                 + (size_t)(bg0 + blo) * HH + jg0 + jloc, val);
            } else {
                if (doL1) sys_st(out + ((size_t)(p - 1) * BATCH + bg0 + blo) * HH + jg0 + jloc, val);
            }
        }
        wait_vm0();
        __syncthreads();                                   // S3: all stores drained

        // 7. group barrier: relaxed RMW arrival + relaxed poll at the LLC
        if (tid == 0) {
            __hip_atomic_fetch_add(mycnt, 1u, __ATOMIC_RELAXED, __HIP_MEMORY_SCOPE_SYSTEM);
            target += WPG;
            if (!dead) {
                unsigned spins = 0;
                while (__hip_atomic_load(mycnt, __ATOMIC_RELAXED, __HIP_MEMORY_SCOPE_SYSTEM) < target) {
                    __builtin_amdgcn_s_sleep(2);
                    if (++spins > (1u << 21)) { dead = true; break; }
                }
            }
            asm volatile("" ::: "memory");
        } else {
            target += WPG;
        }
        __syncthreads();                                   // S4
    }
}

extern "C" void kernel_launch(void* const* d_in, const int* in_sizes, int n_in,
                              void* d_out, int out_size, void* d_ws, size_t ws_size,
                              hipStream_t stream) {
    (void)in_sizes; (void)n_in; (void)out_size; (void)ws_size;
    const float* Xt   = (const float*)d_in[0];
    const float* Wih0 = (const float*)d_in[1];
    const float* bih0 = (const float*)d_in[2];
    const float* Whh0 = (const float*)d_in[3];
    const float* bhh0 = (const float*)d_in[4];
    const float* Wih1 = (const float*)d_in[5];
    const float* bih1 = (const float*)d_in[6];
    const float* Whh1 = (const float*)d_in[7];
    const float* bhh1 = (const float*)d_in[8];
    float*    out   = (float*)d_out;
    float*    h0buf = (float*)d_ws;                          // 2*64*512 floats
    unsigned* cnt   = (unsigned*)((char*)d_ws + 2 * BATCH * HH * 4);  // 8 counters, 256B stride

    hipFuncSetAttribute((const void*)elman_persistent,
                        hipFuncAttributeMaxDynamicSharedMemorySize, LDS_BYTES);
    hipMemsetAsync(d_ws, 0, 2 * BATCH * HH * 4 + NG * 256, stream);

    // 1) Z0 = Xt@Wih0^T + bih0 -> out
    z0_gemm<<<dim3((TT * BATCH / 64) * (HH / 64)), dim3(256), 0, stream>>>(
        Xt, Wih0, bih0, out);

    // 2) persistent recurrence (3 matmuls/phase)
    elman_persistent<<<dim3(NG * WPG), dim3(NTH), LDS_BYTES, stream>>>(
        Whh0, bhh0, Wih1, bih1, Whh1, bhh1, out, h0buf, cnt);
}